// Round 3
// baseline (105.467 us; speedup 1.0000x reference)
//
#include <hip/hip_runtime.h>
#include <math.h>

#define DD 128
#define NSPLIT 32
#define NBINS 512
#define SHIFT 10.0f
#define L2E_T 14.4269504089f   // 10 * log2(e)

typedef _Float16 f16x8 __attribute__((ext_vector_type(8)));
typedef _Float16 f16x2 __attribute__((ext_vector_type(2)));
typedef float f32x4 __attribute__((ext_vector_type(4)));

// ---- normalize rows (fp32), emit f16 copy, labels, histogram, label-sums G ----
__global__ __launch_bounds__(256)
void norm_kernel(const float* __restrict__ f, const int* __restrict__ labels,
                 float* __restrict__ fn, _Float16* __restrict__ fh,
                 int* __restrict__ labm, int* __restrict__ hist,
                 float* __restrict__ G, int M, int nrep)
{
    int gw = (blockIdx.x * 256 + threadIdx.x) >> 6;   // one wave per row
    int lane = threadIdx.x & 63;
    if (gw >= M) return;
    float2 v = *reinterpret_cast<const float2*>(&f[(size_t)gw * DD + lane * 2]);
    float ss = v.x * v.x + v.y * v.y;
    #pragma unroll
    for (int m = 1; m < 64; m <<= 1) ss += __shfl_xor(ss, m);
    float inv = 1.0f / fmaxf(sqrtf(ss), 1e-12f);
    float2 o; o.x = v.x * inv; o.y = v.y * inv;
    *reinterpret_cast<float2*>(&fn[(size_t)gw * DD + lane * 2]) = o;
    f16x2 h; h[0] = (_Float16)o.x; h[1] = (_Float16)o.y;
    *reinterpret_cast<f16x2*>(&fh[(size_t)gw * DD + lane * 2]) = h;
    int lb = labels[gw / nrep];
    atomicAdd(&G[lb * DD + lane * 2],     o.x);
    atomicAdd(&G[lb * DD + lane * 2 + 1], o.y);
    if (lane == 0) { labm[gw] = lb; atomicAdd(&hist[lb], 1); }
}

// ---- main: f16 MFMA over all pairs, fused exp-sum. No LDS, no masks. ----
// Block: 4 waves; wave owns 64 i-rows whose B-fragments are register-resident
// (4 subtiles x 4 K-steps = 64 VGPR). j streams in 16-row A-tiles, software-
// pipelined ping-pong (A0/A1): each 16-MFMA compute phase covers the other
// buffer's 4 L2 loads. S^T tiles via mfma(A=Fj, B=Fi): i is lane-local
// (col = lane&15) so E_i accumulates per-lane; j spans (lane>>4, reg).
__global__ __launch_bounds__(256, 4)
void supcon_main(const _Float16* __restrict__ fh, float* __restrict__ Epart,
                 int M, int jchunk)
{
    const int lane = threadIdx.x & 63;
    const int w = threadIdx.x >> 6;
    const int ibase = blockIdx.x * 256 + w * 64;
    const int rowsel = lane & 15;
    const int ksel = (lane >> 4) * 8;     // f16 k-offset within 32-wide K step

    // register-resident Fi fragments: 4 subtiles x 4 K-steps
    f16x8 bfr[4][4];
    #pragma unroll
    for (int t = 0; t < 4; ++t)
        #pragma unroll
        for (int kk = 0; kk < 4; ++kk)
            bfr[t][kk] = *reinterpret_cast<const f16x8*>(
                &fh[(size_t)(ibase + t * 16 + rowsel) * DD + kk * 32 + ksel]);

    float esum[4] = {0.f, 0.f, 0.f, 0.f};
    const int jstart = blockIdx.y * jchunk;
    const int ntile = jchunk >> 4;        // 16 j rows per tile
    const _Float16* aptr = fh + (size_t)(jstart + rowsel) * DD + ksel;
    const int TS = 16 * DD;               // halves per j-tile

#define LOADA(buf, tile) { \
    _Pragma("unroll") \
    for (int kk = 0; kk < 4; ++kk) \
        buf[kk] = *reinterpret_cast<const f16x8*>(aptr + (size_t)(tile) * TS + kk * 32); }

#define COMPUTE(buf) { \
    _Pragma("unroll") \
    for (int t = 0; t < 4; ++t) { \
        f32x4 acc = {0.f, 0.f, 0.f, 0.f}; \
        _Pragma("unroll") \
        for (int kk = 0; kk < 4; ++kk) \
            acc = __builtin_amdgcn_mfma_f32_16x16x32_f16(buf[kk], bfr[t][kk], acc, 0, 0, 0); \
        _Pragma("unroll") \
        for (int r = 0; r < 4; ++r) \
            esum[t] += exp2f(__builtin_fmaf(acc[r], L2E_T, -L2E_T)); } }

    f16x8 A0[4], A1[4];
    LOADA(A0, 0);
    LOADA(A1, 1);
    for (int jt = 0; jt < ntile; jt += 2) {
        COMPUTE(A0);
        int j2 = (jt + 2 < ntile) ? jt + 2 : jt;      // tail: redundant reload
        LOADA(A0, j2);
        COMPUTE(A1);
        int j3 = (jt + 3 < ntile) ? jt + 3 : jt + 1;
        LOADA(A1, j3);
    }
#undef LOADA
#undef COMPUTE

    // lane groups (bits 4,5) hold different j-rows of the same i: fold them
    #pragma unroll
    for (int t = 0; t < 4; ++t) {
        float e = esum[t];
        e += __shfl_xor(e, 16);
        e += __shfl_xor(e, 32);
        if (lane < 16)
            Epart[(size_t)blockIdx.y * M + ibase + t * 16 + lane] = e;
    }
}

// ---- fused per-row loss term + global reduction ----
__global__ __launch_bounds__(256)
void final_fused(const float* __restrict__ fn, const float* __restrict__ Epart,
                 const int* __restrict__ labm, const int* __restrict__ hist,
                 const float* __restrict__ G, float* __restrict__ out, int M)
{
    __shared__ float red[4];
    int i = (blockIdx.x * 256 + threadIdx.x) >> 6;   // wave per row (M % 4 == 0)
    int lane = threadIdx.x & 63;
    int lb = labm[i];
    float2 v = *reinterpret_cast<const float2*>(&fn[(size_t)i * DD + lane * 2]);
    float2 g = *reinterpret_cast<const float2*>(&G[lb * DD + lane * 2]);
    float gd = v.x * g.x + v.y * g.y;   // f_i . G[lab_i]
    float sd = v.x * v.x + v.y * v.y;   // f_i . f_i
    #pragma unroll
    for (int m = 1; m < 64; m <<= 1) { gd += __shfl_xor(gd, m); sd += __shfl_xor(sd, m); }
    float e = (lane < NSPLIT) ? Epart[(size_t)lane * M + i] : 0.f;
    #pragma unroll
    for (int m = 1; m < NSPLIT; m <<= 1) e += __shfl_xor(e, m);
    float term = 0.f;
    if (lane == 0) {
        float E = e - 1.0f;                        // drop diagonal exp(0)
        float cnt = (float)(hist[lb] - 1);
        term = (SHIFT + logf(E)) - SHIFT * (gd - sd) / cnt;
    }
    int wv = threadIdx.x >> 6;
    if (lane == 0) red[wv] = term;
    __syncthreads();
    if (threadIdx.x == 0)
        atomicAdd(out, (red[0] + red[1] + red[2] + red[3]) / (float)M);
}

extern "C" void kernel_launch(void* const* d_in, const int* in_sizes, int n_in,
                              void* d_out, int out_size, void* d_ws, size_t ws_size,
                              hipStream_t stream)
{
    const float* feats = (const float*)d_in[0];
    const int* labels = (const int*)d_in[1];
    const int Bn = in_sizes[1];
    const int M = in_sizes[0] / DD;    // 8192
    const int nrep = M / Bn;           // 2

    char* ws = (char*)d_ws;
    float* fn = (float*)ws;
    size_t off = (size_t)M * DD * sizeof(float);
    _Float16* fh = (_Float16*)(ws + off); off += (size_t)M * DD * sizeof(_Float16);
    int* labm = (int*)(ws + off); off += (size_t)M * sizeof(int);
    off = (off + 255) & ~(size_t)255;
    float* G = (float*)(ws + off); off += (size_t)NBINS * DD * sizeof(float);
    int* hist = (int*)(ws + off); off += (size_t)NBINS * sizeof(int);
    float* Epart = (float*)(ws + off); off += (size_t)NSPLIT * M * sizeof(float);

    // G and hist are contiguous: one memset clears both
    hipMemsetAsync(G, 0, (size_t)NBINS * DD * sizeof(float) + NBINS * sizeof(int), stream);
    hipMemsetAsync(d_out, 0, sizeof(float), stream);

    norm_kernel<<<M / 4, 256, 0, stream>>>(feats, labels, fn, fh, labm, hist, G, M, nrep);

    const int jchunk = M / NSPLIT;     // 256
    dim3 grid(M / 256, NSPLIT);        // 32 x 32 = 1024 blocks
    supcon_main<<<grid, 256, 0, stream>>>(fh, Epart, M, jchunk);

    final_fused<<<M / 4, 256, 0, stream>>>(fn, Epart, labm, hist, G, (float*)d_out, M);
}

// Round 4
// 102.805 us; speedup vs baseline: 1.0259x; 1.0259x over previous
//
#include <hip/hip_runtime.h>
#include <math.h>

#define DD 128
#define NSPLIT 32
#define NBINS 512
#define SHIFT 10.0f
#define L2E_T 14.4269504089f   // 10 * log2(e)

typedef _Float16 f16x8 __attribute__((ext_vector_type(8)));
typedef _Float16 f16x2 __attribute__((ext_vector_type(2)));
typedef float f32x4 __attribute__((ext_vector_type(4)));

// ---- normalize rows (fp32), emit f16 copy, labels, histogram, label-sums G ----
__global__ __launch_bounds__(256)
void norm_kernel(const float* __restrict__ f, const int* __restrict__ labels,
                 float* __restrict__ fn, _Float16* __restrict__ fh,
                 int* __restrict__ labm, int* __restrict__ hist,
                 float* __restrict__ G, int M, int nrep)
{
    int gw = (blockIdx.x * 256 + threadIdx.x) >> 6;   // one wave per row
    int lane = threadIdx.x & 63;
    if (gw >= M) return;
    float2 v = *reinterpret_cast<const float2*>(&f[(size_t)gw * DD + lane * 2]);
    float ss = v.x * v.x + v.y * v.y;
    #pragma unroll
    for (int m = 1; m < 64; m <<= 1) ss += __shfl_xor(ss, m);
    float inv = 1.0f / fmaxf(sqrtf(ss), 1e-12f);
    float2 o; o.x = v.x * inv; o.y = v.y * inv;
    *reinterpret_cast<float2*>(&fn[(size_t)gw * DD + lane * 2]) = o;
    f16x2 h; h[0] = (_Float16)o.x; h[1] = (_Float16)o.y;
    *reinterpret_cast<f16x2*>(&fh[(size_t)gw * DD + lane * 2]) = h;
    int lb = labels[gw / nrep];
    atomicAdd(&G[lb * DD + lane * 2],     o.x);
    atomicAdd(&G[lb * DD + lane * 2 + 1], o.y);
    if (lane == 0) { labm[gw] = lb; atomicAdd(&hist[lb], 1); }
}

// ---- main: f16 MFMA over all pairs, fused exp-sum. No LDS, no masks. ----
// Block: 4 waves; wave owns 64 i-rows whose B-fragments are register-resident
// (4 subtiles x 4 K-steps = 64 regs). j streams in 16-row A-tiles, software-
// pipelined ping-pong (A0/A1). launch_bounds(256,3): ~170-reg cap so the
// ~150-reg working set does NOT spill (R3's (256,4)=128-cap spilled: 13 MB
// scratch writes). S^T tiles via mfma(A=Fj, B=Fi): i is lane-local
// (col = lane&15) so E_i accumulates per-lane; j spans (lane>>4, reg).
__global__ __launch_bounds__(256, 3)
void supcon_main(const _Float16* __restrict__ fh, float* __restrict__ Epart,
                 int M, int jchunk)
{
    const int lane = threadIdx.x & 63;
    const int w = threadIdx.x >> 6;
    const int ibase = blockIdx.x * 256 + w * 64;
    const int rowsel = lane & 15;
    const int ksel = (lane >> 4) * 8;     // f16 k-offset within 32-wide K step

    // register-resident Fi fragments: 4 subtiles x 4 K-steps
    f16x8 bfr[4][4];
    #pragma unroll
    for (int t = 0; t < 4; ++t)
        #pragma unroll
        for (int kk = 0; kk < 4; ++kk)
            bfr[t][kk] = *reinterpret_cast<const f16x8*>(
                &fh[(size_t)(ibase + t * 16 + rowsel) * DD + kk * 32 + ksel]);

    // dual accumulators per subtile: halves the dependent-add chain
    float esumA[4] = {0.f, 0.f, 0.f, 0.f};
    float esumB[4] = {0.f, 0.f, 0.f, 0.f};
    const int jstart = blockIdx.y * jchunk;
    const int ntile = jchunk >> 4;        // 16 j rows per tile (even count)
    const _Float16* aptr = fh + (size_t)(jstart + rowsel) * DD + ksel;
    const int TS = 16 * DD;               // halves per j-tile

#define LOADA(buf, tile) { \
    _Pragma("unroll") \
    for (int kk = 0; kk < 4; ++kk) \
        buf[kk] = *reinterpret_cast<const f16x8*>(aptr + (size_t)(tile) * TS + kk * 32); }

#define COMPUTE(buf) { \
    _Pragma("unroll") \
    for (int t = 0; t < 4; ++t) { \
        f32x4 acc = {0.f, 0.f, 0.f, 0.f}; \
        _Pragma("unroll") \
        for (int kk = 0; kk < 4; ++kk) \
            acc = __builtin_amdgcn_mfma_f32_16x16x32_f16(buf[kk], bfr[t][kk], acc, 0, 0, 0); \
        esumA[t] += exp2f(__builtin_fmaf(acc[0], L2E_T, -L2E_T)); \
        esumB[t] += exp2f(__builtin_fmaf(acc[1], L2E_T, -L2E_T)); \
        esumA[t] += exp2f(__builtin_fmaf(acc[2], L2E_T, -L2E_T)); \
        esumB[t] += exp2f(__builtin_fmaf(acc[3], L2E_T, -L2E_T)); } }

    f16x8 A0[4], A1[4];
    LOADA(A0, 0);
    LOADA(A1, 1);
    int jt = 0;
    for (; jt + 2 < ntile; jt += 2) {
        COMPUTE(A0);
        LOADA(A0, jt + 2);
        COMPUTE(A1);
        LOADA(A1, jt + 3);
    }
    COMPUTE(A0);
    COMPUTE(A1);
#undef LOADA
#undef COMPUTE

    // lane groups (bits 4,5) hold different j-rows of the same i: fold them
    #pragma unroll
    for (int t = 0; t < 4; ++t) {
        float e = esumA[t] + esumB[t];
        e += __shfl_xor(e, 16);
        e += __shfl_xor(e, 32);
        if (lane < 16)
            Epart[(size_t)blockIdx.y * M + ibase + t * 16 + lane] = e;
    }
}

// ---- fused per-row loss term + global reduction ----
__global__ __launch_bounds__(256)
void final_fused(const float* __restrict__ fn, const float* __restrict__ Epart,
                 const int* __restrict__ labm, const int* __restrict__ hist,
                 const float* __restrict__ G, float* __restrict__ out, int M)
{
    __shared__ float red[4];
    int i = (blockIdx.x * 256 + threadIdx.x) >> 6;   // wave per row (M % 4 == 0)
    int lane = threadIdx.x & 63;
    int lb = labm[i];
    float2 v = *reinterpret_cast<const float2*>(&fn[(size_t)i * DD + lane * 2]);
    float2 g = *reinterpret_cast<const float2*>(&G[lb * DD + lane * 2]);
    float gd = v.x * g.x + v.y * g.y;   // f_i . G[lab_i]
    float sd = v.x * v.x + v.y * v.y;   // f_i . f_i
    #pragma unroll
    for (int m = 1; m < 64; m <<= 1) { gd += __shfl_xor(gd, m); sd += __shfl_xor(sd, m); }
    float e = (lane < NSPLIT) ? Epart[(size_t)lane * M + i] : 0.f;
    #pragma unroll
    for (int m = 1; m < NSPLIT; m <<= 1) e += __shfl_xor(e, m);
    float term = 0.f;
    if (lane == 0) {
        float E = e - 1.0f;                        // drop diagonal exp(0)
        float cnt = (float)(hist[lb] - 1);
        term = (SHIFT + logf(E)) - SHIFT * (gd - sd) / cnt;
    }
    int wv = threadIdx.x >> 6;
    if (lane == 0) red[wv] = term;
    __syncthreads();
    if (threadIdx.x == 0)
        atomicAdd(out, (red[0] + red[1] + red[2] + red[3]) / (float)M);
}

extern "C" void kernel_launch(void* const* d_in, const int* in_sizes, int n_in,
                              void* d_out, int out_size, void* d_ws, size_t ws_size,
                              hipStream_t stream)
{
    const float* feats = (const float*)d_in[0];
    const int* labels = (const int*)d_in[1];
    const int Bn = in_sizes[1];
    const int M = in_sizes[0] / DD;    // 8192
    const int nrep = M / Bn;           // 2

    char* ws = (char*)d_ws;
    float* fn = (float*)ws;
    size_t off = (size_t)M * DD * sizeof(float);
    _Float16* fh = (_Float16*)(ws + off); off += (size_t)M * DD * sizeof(_Float16);
    int* labm = (int*)(ws + off); off += (size_t)M * sizeof(int);
    off = (off + 255) & ~(size_t)255;
    float* G = (float*)(ws + off); off += (size_t)NBINS * DD * sizeof(float);
    int* hist = (int*)(ws + off); off += (size_t)NBINS * sizeof(int);
    float* Epart = (float*)(ws + off); off += (size_t)NSPLIT * M * sizeof(float);

    // G and hist are contiguous: one memset clears both
    hipMemsetAsync(G, 0, (size_t)NBINS * DD * sizeof(float) + NBINS * sizeof(int), stream);
    hipMemsetAsync(d_out, 0, sizeof(float), stream);

    norm_kernel<<<M / 4, 256, 0, stream>>>(feats, labels, fn, fh, labm, hist, G, M, nrep);

    const int jchunk = M / NSPLIT;     // 256
    dim3 grid(M / 256, NSPLIT);        // 32 x 32 = 1024 blocks
    supcon_main<<<grid, 256, 0, stream>>>(fh, Epart, M, jchunk);

    final_fused<<<M / 4, 256, 0, stream>>>(fn, Epart, labm, hist, G, (float*)d_out, M);
}